// Round 1
// baseline (293.832 us; speedup 1.0000x reference)
//
#include <hip/hip_runtime.h>

// FlowNetC correlation on MI355X.
// out[b, dyi*21+dxi, y, x] = (1/128) * sum_c in1[b,c,y,x] * in2[b,c,y+dy,x+dx]
//   dy = 2*(dyi-10), dx = 2*(dxi-10); in2 treated as zero outside [0,96)^2.
//
// Structure (round 1):
//  - grid (12 y-tiles, 21 dy, 4 batch), block 192 threads (3 waves)
//  - channel chunks of 8 staged in LDS; in1 and in2 stored PARITY-SPLIT so the
//    21 even displacements become contiguous -> ds_read_b128
//  - each thread: 4 x-positions (same parity) x 21 dx = 84 fp32 accumulators
//  - border / out-of-range-row zeros in lds2 are chunk-invariant: written once

#define BB 4
#define CC_ALL 128
#define HH 96
#define WW 96
#define ND 21
#define MD 20
#define TY 8            // rows per block
#define CC 8            // channels per chunk
#define NCHUNK (CC_ALL / CC)
#define GX 4            // x-positions (one parity) per thread
#define UNITS 24        // per row: 2 parities * 12 units of GX
#define NTHR (TY * UNITS)   // 192
#define W2 68           // per-parity in2 row width: X in [-20,116) -> 68 per parity
#define LDS1_ROW 48     // per-parity in1 row width

__global__ __launch_bounds__(NTHR, 2)
void corr_kernel(const float* __restrict__ in1,
                 const float* __restrict__ in2,
                 float* __restrict__ out) {
    __shared__ float lds1[CC * TY * 2 * LDS1_ROW];  // 6144 f = 24 KB
    __shared__ float lds2[CC * TY * 2 * W2];        // 8704 f = 34 KB

    const int tid = threadIdx.x;
    const int y0  = blockIdx.x * TY;
    const int dyi = blockIdx.y;            // 0..20
    const int b   = blockIdx.z;
    const int dy  = 2 * (dyi - 10);

    // compute-phase mapping
    const int r   = tid / UNITS;           // 0..7
    const int un_ = tid % UNITS;
    const int p   = un_ / 12;              // parity
    const int u0  = (un_ % 12) * GX;       // 0,4,...,44

    float acc[ND * GX];
#pragma unroll
    for (int i = 0; i < ND * GX; ++i) acc[i] = 0.f;

    const float* in1b = in1 + b * (CC_ALL * HH * WW);
    const float* in2b = in2 + b * (CC_ALL * HH * WW);

    // one-time zero fill of lds2: borders (X<0 or X>=96) and rows with
    // y+dy out of range stay zero for every chunk (never overwritten).
    {
        float4 z = make_float4(0.f, 0.f, 0.f, 0.f);
        for (int k = tid; k < (CC * TY * 2 * W2) / 4; k += NTHR)
            ((float4*)lds2)[k] = z;
    }

    for (int ch = 0; ch < NCHUNK; ++ch) {
        const int c0 = ch * CC;
        __syncthreads();   // covers zero-init (first iter) / prior compute reads

        // ---- stage in1 chunk: CC*TY rows of 96 floats, as float4 ----
#pragma unroll
        for (int k = 0; k < 8; ++k) {
            int f  = tid + k * NTHR;          // 0..1535
            int x4 = f % 24;
            int rc = f / 24;                  // 0..63 = c*8 + rr
            int c  = rc >> 3, rr = rc & 7;
            const float4 g = *(const float4*)&in1b[(c0 + c) * (HH * WW) + (y0 + rr) * WW + x4 * 4];
            float* base = &lds1[(c * TY + rr) * 2 * LDS1_ROW];
            // x = 4*x4 + j; parity j&1; index x/2 = 2*x4 + (j>>1)
            base[             2 * x4    ] = g.x;
            base[             2 * x4 + 1] = g.z;
            base[LDS1_ROW +   2 * x4    ] = g.y;
            base[LDS1_ROW +   2 * x4 + 1] = g.w;
        }

        // ---- stage in2 chunk interior (X in [0,96)), rows y0+rr+dy ----
#pragma unroll
        for (int k = 0; k < 8; ++k) {
            int f  = tid + k * NTHR;
            int x4 = f % 24;
            int rc = f / 24;
            int c  = rc >> 3, rr = rc & 7;
            int Y  = y0 + rr + dy;
            if ((unsigned)Y < HH) {
                const float4 g = *(const float4*)&in2b[(c0 + c) * (HH * WW) + Y * WW + x4 * 4];
                float* base = &lds2[(c * TY + rr) * 2 * W2];
                // X = 4*x4 + j; e = X+20; slot = [e&1][e>>1] = [j&1][2*x4+10+(j>>1)]
                base[      2 * x4 + 10] = g.x;
                base[      2 * x4 + 11] = g.z;
                base[W2 +  2 * x4 + 10] = g.y;
                base[W2 +  2 * x4 + 11] = g.w;
            }
        }
        __syncthreads();

        // ---- compute: per channel, 1+6 b128 LDS reads feed 84 FMAs ----
#pragma unroll
        for (int c = 0; c < CC; ++c) {
            const float* a4  = &lds1[((c * TY + r) * 2 + p) * LDS1_ROW + u0];
            const float* v24 = &lds2[((c * TY + r) * 2 + p) * W2 + u0];
            float4 af = *(const float4*)a4;
            float v[24];
#pragma unroll
            for (int m = 0; m < 24; m += 4) {
                float4 t = *(const float4*)&v24[m];
                v[m] = t.x; v[m + 1] = t.y; v[m + 2] = t.z; v[m + 3] = t.w;
            }
#pragma unroll
            for (int id = 0; id < ND; ++id) {
                acc[id * GX + 0] += af.x * v[id + 0];
                acc[id * GX + 1] += af.y * v[id + 1];
                acc[id * GX + 2] += af.z * v[id + 2];
                acc[id * GX + 3] += af.w * v[id + 3];
            }
        }
    }

    // ---- epilogue: scale and write ----
    const float scale = 1.0f / 128.0f;
#pragma unroll
    for (int id = 0; id < ND; ++id) {
        int d = dyi * ND + id;
        int base = ((b * (ND * ND) + d) * HH + (y0 + r)) * WW;
#pragma unroll
        for (int j = 0; j < GX; ++j) {
            int x = 2 * (u0 + j) + p;
            out[base + x] = acc[id * GX + j] * scale;
        }
    }
}

extern "C" void kernel_launch(void* const* d_in, const int* in_sizes, int n_in,
                              void* d_out, int out_size, void* d_ws, size_t ws_size,
                              hipStream_t stream) {
    const float* in1 = (const float*)d_in[0];
    const float* in2 = (const float*)d_in[1];
    float* out = (float*)d_out;
    dim3 grid(HH / TY, ND, BB);
    dim3 block(NTHR);
    hipLaunchKernelGGL(corr_kernel, grid, block, 0, stream, in1, in2, out);
}